// Round 1
// baseline (283.058 us; speedup 1.0000x reference)
//
#include <hip/hip_runtime.h>
#include <hip/hip_bf16.h>
#include <math.h>

#define T_TOK  16384
#define HC_N   4
#define H_DIM  512
#define NHEADS 12
#define E_DIM  768
#define NCOLS  2560   // 4*512 keys + 512 v
#define EPS_N  1e-5f

typedef unsigned short u16;
typedef __bf16 bf16;
typedef bf16   bf16x8 __attribute__((ext_vector_type(8)));
typedef float  f32x4  __attribute__((ext_vector_type(4)));
typedef u16    u16x4  __attribute__((ext_vector_type(4)));
typedef u16    u16x8  __attribute__((ext_vector_type(8)));

__device__ __forceinline__ u16 f2bf(float f) {
  unsigned u = __builtin_bit_cast(unsigned, f);
  unsigned r = u + 0x7fffu + ((u >> 16) & 1u);
  return (u16)(r >> 16);
}
__device__ __forceinline__ float bf2f(u16 h) {
  unsigned u = ((unsigned)h) << 16;
  return __builtin_bit_cast(float, u);
}
__device__ __forceinline__ float wave_sum(float v) {
  #pragma unroll
  for (int off = 32; off; off >>= 1) v += __shfl_xor(v, off, 64);
  return v;
}

// ---------------- Kernel A: gather embedding rows, cast to bf16 -------------
__global__ __launch_bounds__(256) void gather_emb(
    const int* __restrict__ hash_ids, const int* __restrict__ offsets,
    const float* __restrict__ emb_w, u16* __restrict__ emb) {
  int idx = blockIdx.x * 256 + threadIdx.x;        // T*768 total
  int t = idx / E_DIM;
  int e = idx - t * E_DIM;
  int head = e >> 6, d = e & 63;
  int row = hash_ids[t * NHEADS + head] + offsets[head];
  emb[idx] = f2bf(emb_w[(size_t)row * 64 + d]);
}

// ---------------- Kernel A2: build WcatT (2560 x 768) bf16 ------------------
// WcatT[n][e]: n<2048 -> key_projs_w[n>>9][e][n&511]; n>=2048 -> v_proj_w[e][n-2048]
__global__ __launch_bounds__(256) void build_wcat(
    const float* __restrict__ kp, const float* __restrict__ vp,
    u16* __restrict__ wt) {
  __shared__ float tile[32][33];
  int m = blockIdx.z;
  const float* src = (m < 4) ? (kp + (size_t)m * E_DIM * H_DIM) : vp;
  int h0 = blockIdx.x * 32, e0 = blockIdx.y * 32;
  int tx = threadIdx.x, ty = threadIdx.y;          // block (32,8)
  #pragma unroll
  for (int j = 0; j < 32; j += 8)
    tile[ty + j][tx] = src[(size_t)(e0 + ty + j) * H_DIM + h0 + tx];
  __syncthreads();
  #pragma unroll
  for (int j = 0; j < 32; j += 8) {
    int h = h0 + ty + j, e = e0 + tx;
    wt[(size_t)(m * H_DIM + h) * E_DIM + e] = f2bf(tile[tx][ty + j]);
  }
}

// ---------------- Kernel B: bf16 MFMA GEMM, C = A(16384x768) * BT^T ----------
// A row-major (M,K), BT row-major (N,K); out S bf16 (M, 2560)
__global__ __launch_bounds__(256, 2) void gemm_bf16(
    const u16* __restrict__ A, const u16* __restrict__ BT, u16* __restrict__ S) {
  __shared__ u16 As[128][64];
  __shared__ u16 Bs[128][64];
  const int K = E_DIM;
  int tid = threadIdx.x;
  int lane = tid & 63, wid = tid >> 6;
  int bx = blockIdx.x, by = blockIdx.y;            // bx: N tile (20), by: M tile (128)
  int wm = (wid >> 1) * 64, wn = (wid & 1) * 64;

  const u16* aptr = A + (size_t)(by * 128 + (tid >> 3)) * K + (tid & 7) * 8;
  const u16* bptr = BT + (size_t)(bx * 128 + (tid >> 3)) * K + (tid & 7) * 8;
  int lds_off = tid * 16;                           // bytes

  f32x4 acc[4][4] = {};

  for (int k0 = 0; k0 < K; k0 += 64) {
    #pragma unroll
    for (int r = 0; r < 4; ++r) {
      __builtin_amdgcn_global_load_lds(
        (const __attribute__((address_space(1))) void*)(aptr + (size_t)(r * 32) * K + k0),
        (__attribute__((address_space(3))) void*)((char*)&As[0][0] + r * 4096 + lds_off),
        16, 0, 0);
      __builtin_amdgcn_global_load_lds(
        (const __attribute__((address_space(1))) void*)(bptr + (size_t)(r * 32) * K + k0),
        (__attribute__((address_space(3))) void*)((char*)&Bs[0][0] + r * 4096 + lds_off),
        16, 0, 0);
    }
    __syncthreads();
    int lr = lane & 15, lk8 = (lane >> 4) * 8;
    #pragma unroll
    for (int kk = 0; kk < 2; ++kk) {
      bf16x8 af[4], bfv[4];
      #pragma unroll
      for (int m = 0; m < 4; ++m)
        af[m] = *reinterpret_cast<const bf16x8*>(&As[wm + m * 16 + lr][kk * 32 + lk8]);
      #pragma unroll
      for (int n = 0; n < 4; ++n)
        bfv[n] = *reinterpret_cast<const bf16x8*>(&Bs[wn + n * 16 + lr][kk * 32 + lk8]);
      #pragma unroll
      for (int m = 0; m < 4; ++m)
        #pragma unroll
        for (int n = 0; n < 4; ++n)
          acc[m][n] = __builtin_amdgcn_mfma_f32_16x16x32_bf16(af[m], bfv[n], acc[m][n], 0, 0, 0);
    }
    __syncthreads();
  }

  int crow0 = by * 128 + wm + (lane >> 4) * 4;
  int ccol0 = bx * 128 + wn + (lane & 15);
  #pragma unroll
  for (int m = 0; m < 4; ++m)
    #pragma unroll
    for (int n = 0; n < 4; ++n)
      #pragma unroll
      for (int j = 0; j < 4; ++j)
        S[(size_t)(crow0 + m * 16 + j) * NCOLS + ccol0 + n * 16] = f2bf(acc[m][n][j]);
}

// ---------------- Kernel C: RMS norms + gate + value + conv-input norm ------
__global__ __launch_bounds__(256) void fuse_gate(
    const float* __restrict__ hidden,   // (T,4,512)
    const u16* __restrict__ S,          // (T,2560) bf16
    const float* __restrict__ qw, const float* __restrict__ kw,
    const float* __restrict__ cw,
    float* __restrict__ out,            // value (T,4,512)
    u16* __restrict__ xn) {             // (T,2048) bf16
  int t = blockIdx.x;
  int g = threadIdx.x >> 6;
  int lane = threadIdx.x & 63;
  int base = lane * 8;

  const float* hp = hidden + (size_t)t * 2048 + g * 512 + base;
  const u16*  sp = S + (size_t)t * 2560 + g * 512 + base;
  const u16*  vpp = S + (size_t)t * 2560 + 2048 + base;

  float4 q0 = *(const float4*)hp;
  float4 q1 = *(const float4*)(hp + 4);
  float q[8] = {q0.x, q0.y, q0.z, q0.w, q1.x, q1.y, q1.z, q1.w};
  u16x8 k8 = *(const u16x8*)sp;
  u16x8 v8 = *(const u16x8*)vpp;
  float k[8], v[8];
  float qss = 0.f, kss = 0.f;
  #pragma unroll
  for (int j = 0; j < 8; ++j) { qss += q[j] * q[j]; k[j] = bf2f(k8[j]); kss += k[j] * k[j]; }
  qss = wave_sum(qss); kss = wave_sum(kss);
  float qinv = rsqrtf(qss * (1.0f / 512.0f) + EPS_N);
  float kinv = rsqrtf(kss * (1.0f / 512.0f) + EPS_N);
  float dot = 0.f;
  #pragma unroll
  for (int j = 0; j < 8; ++j) {
    float qn = q[j] * qinv * qw[g * 512 + base + j];
    float kn = k[j] * kinv * kw[g * 512 + base + j];
    dot += qn * kn;
  }
  dot = wave_sum(dot);
  float gate = 1.0f / (1.0f + __expf(-dot * 0.04419417382415922f));

  float vss = 0.f;
  #pragma unroll
  for (int j = 0; j < 8; ++j) { v[j] = gate * bf2f(v8[j]); vss += v[j] * v[j]; }
  float* op = out + (size_t)t * 2048 + g * 512 + base;
  *(float4*)op       = make_float4(v[0], v[1], v[2], v[3]);
  *(float4*)(op + 4) = make_float4(v[4], v[5], v[6], v[7]);

  vss = wave_sum(vss);
  float vinv = rsqrtf(vss * (1.0f / 512.0f) + EPS_N);
  u16* xp = xn + (size_t)t * 2048 + g * 512 + base;
  u16x8 xo;
  #pragma unroll
  for (int j = 0; j < 8; ++j) xo[j] = f2bf(v[j] * vinv * cw[g * 512 + base + j]);
  *(u16x8*)xp = xo;
}

// ---------------- Kernel D: dilated causal depthwise conv + silu + add ------
__global__ __launch_bounds__(256) void conv_silu_add(
    const u16* __restrict__ xn, const float* __restrict__ conv_w,
    float* __restrict__ out) {
  int idx = blockIdx.x * 256 + threadIdx.x;        // T*512 threads, 4 chans each
  int t = idx >> 9;
  int c4 = (idx & 511) * 4;
  float x[4][4];
  #pragma unroll
  for (int kk = 0; kk < 4; ++kk) {
    int tk = t - 12 + 4 * kk;
    if (tk >= 0) {
      u16x4 xv = *(const u16x4*)&xn[(size_t)tk * 2048 + c4];
      #pragma unroll
      for (int j = 0; j < 4; ++j) x[kk][j] = bf2f(xv[j]);
    } else {
      #pragma unroll
      for (int j = 0; j < 4; ++j) x[kk][j] = 0.f;
    }
  }
  float4 res = *(float4*)&out[(size_t)t * 2048 + c4];
  float r[4] = {res.x, res.y, res.z, res.w};
  #pragma unroll
  for (int j = 0; j < 4; ++j) {
    float4 w = *(const float4*)&conv_w[(c4 + j) * 4];
    float y = w.x * x[0][j] + w.y * x[1][j] + w.z * x[2][j] + w.w * x[3][j];
    r[j] += y / (1.0f + __expf(-y));
  }
  *(float4*)&out[(size_t)t * 2048 + c4] = make_float4(r[0], r[1], r[2], r[3]);
}

extern "C" void kernel_launch(void* const* d_in, const int* in_sizes, int n_in,
                              void* d_out, int out_size, void* d_ws, size_t ws_size,
                              hipStream_t stream) {
  const int*   hash_ids = (const int*)d_in[0];
  const int*   offsets  = (const int*)d_in[1];
  const float* emb_w    = (const float*)d_in[2];
  const float* kp       = (const float*)d_in[3];
  const float* qw       = (const float*)d_in[4];
  const float* kw       = (const float*)d_in[5];
  const float* vp       = (const float*)d_in[6];
  const float* conv_w   = (const float*)d_in[7];
  const float* cw       = (const float*)d_in[8];
  const float* hidden   = (const float*)d_in[9];
  float* out = (float*)d_out;
  char*  ws  = (char*)d_ws;

  u16* S   = (u16*)ws;                          // 16384*2560*2 = 83,886,080
  u16* emb = (u16*)(ws + 83886080);             // 16384*768*2  = 25,165,824
  u16* wt  = (u16*)(ws + 109051904);            // 2560*768*2   =  3,932,160
  u16* xn  = (u16*)(ws + 112984064);            // 16384*2048*2 = 67,108,864

  gather_emb<<<(T_TOK * E_DIM) / 256, 256, 0, stream>>>(hash_ids, offsets, emb_w, emb);
  build_wcat<<<dim3(16, 24, 5), dim3(32, 8), 0, stream>>>(kp, vp, wt);
  gemm_bf16<<<dim3(20, 128), 256, 0, stream>>>(emb, wt, S);
  fuse_gate<<<T_TOK, 256, 0, stream>>>(hidden, S, qw, kw, cw, out, xn);
  conv_silu_add<<<(T_TOK * 512) / 256, 256, 0, stream>>>(xn, conv_w, out);
}

// Round 2
// 205.266 us; speedup vs baseline: 1.3790x; 1.3790x over previous
//
#include <hip/hip_runtime.h>
#include <hip/hip_bf16.h>
#include <math.h>

#define T_TOK  16384
#define HC_N   4
#define H_DIM  512
#define NHEADS 12
#define E_DIM  768
#define NCOLS  2560   // 4*512 keys + 512 v
#define EPS_N  1e-5f

typedef unsigned short u16;
typedef __bf16 bf16;
typedef bf16   bf16x8 __attribute__((ext_vector_type(8)));
typedef float  f32x4  __attribute__((ext_vector_type(4)));
typedef u16    u16x2  __attribute__((ext_vector_type(2)));
typedef u16    u16x4  __attribute__((ext_vector_type(4)));
typedef u16    u16x8  __attribute__((ext_vector_type(8)));

__device__ __forceinline__ u16 f2bf(float f) {
  unsigned u = __builtin_bit_cast(unsigned, f);
  unsigned r = u + 0x7fffu + ((u >> 16) & 1u);
  return (u16)(r >> 16);
}
__device__ __forceinline__ float bf2f(u16 h) {
  unsigned u = ((unsigned)h) << 16;
  return __builtin_bit_cast(float, u);
}
__device__ __forceinline__ float wave_sum(float v) {
  #pragma unroll
  for (int off = 32; off; off >>= 1) v += __shfl_xor(v, off, 64);
  return v;
}
__device__ __forceinline__ void wave_sum3(float& a, float& b, float& c) {
  #pragma unroll
  for (int off = 32; off; off >>= 1) {
    a += __shfl_xor(a, off, 64);
    b += __shfl_xor(b, off, 64);
    c += __shfl_xor(c, off, 64);
  }
}

// ---------------- Kernel A: gather embedding rows, cast to bf16 -------------
__global__ __launch_bounds__(256) void gather_emb(
    const int* __restrict__ hash_ids, const int* __restrict__ offsets,
    const float* __restrict__ emb_w, u16* __restrict__ emb) {
  int idx = blockIdx.x * 256 + threadIdx.x;        // T*768 total
  int t = idx / E_DIM;
  int e = idx - t * E_DIM;
  int head = e >> 6, d = e & 63;
  int row = hash_ids[t * NHEADS + head] + offsets[head];
  emb[idx] = f2bf(emb_w[(size_t)row * 64 + d]);
}

// ---------------- Kernel A2: build WcatT (2560 x 768) bf16 ------------------
__global__ __launch_bounds__(256) void build_wcat(
    const float* __restrict__ kp, const float* __restrict__ vp,
    u16* __restrict__ wt) {
  __shared__ float tile[32][33];
  int m = blockIdx.z;
  const float* src = (m < 4) ? (kp + (size_t)m * E_DIM * H_DIM) : vp;
  int h0 = blockIdx.x * 32, e0 = blockIdx.y * 32;
  int tx = threadIdx.x, ty = threadIdx.y;          // block (32,8)
  #pragma unroll
  for (int j = 0; j < 32; j += 8)
    tile[ty + j][tx] = src[(size_t)(e0 + ty + j) * H_DIM + h0 + tx];
  __syncthreads();
  #pragma unroll
  for (int j = 0; j < 32; j += 8) {
    int h = h0 + ty + j, e = e0 + tx;
    wt[(size_t)(m * H_DIM + h) * E_DIM + e] = f2bf(tile[tx][ty + j]);
  }
}

// ---------------- Kernel A3: fold conv_norm_w into conv weights -------------
// wc[k][cf] = conv_w[cf][k] * conv_norm_w[cf]
__global__ __launch_bounds__(256) void build_wc(
    const float* __restrict__ conv_w, const float* __restrict__ cnw,
    float* __restrict__ wc) {
  int cf = blockIdx.x * 256 + threadIdx.x;         // 2048
  float c = cnw[cf];
  #pragma unroll
  for (int k = 0; k < 4; ++k) wc[k * 2048 + cf] = conv_w[cf * 4 + k] * c;
}

// ---------------- Kernel B: bf16 MFMA GEMM, C = A(16384x768) * BT^T ----------
__global__ __launch_bounds__(256, 2) void gemm_bf16(
    const u16* __restrict__ A, const u16* __restrict__ BT, u16* __restrict__ S) {
  __shared__ u16 As[128][64];
  __shared__ u16 Bs[128][64];
  const int K = E_DIM;
  int tid = threadIdx.x;
  int lane = tid & 63, wid = tid >> 6;
  int bx = blockIdx.x, by = blockIdx.y;
  int wm = (wid >> 1) * 64, wn = (wid & 1) * 64;

  const u16* aptr = A + (size_t)(by * 128 + (tid >> 3)) * K + (tid & 7) * 8;
  const u16* bptr = BT + (size_t)(bx * 128 + (tid >> 3)) * K + (tid & 7) * 8;
  int lds_off = tid * 16;

  f32x4 acc[4][4] = {};

  for (int k0 = 0; k0 < K; k0 += 64) {
    #pragma unroll
    for (int r = 0; r < 4; ++r) {
      __builtin_amdgcn_global_load_lds(
        (const __attribute__((address_space(1))) void*)(aptr + (size_t)(r * 32) * K + k0),
        (__attribute__((address_space(3))) void*)((char*)&As[0][0] + r * 4096 + lds_off),
        16, 0, 0);
      __builtin_amdgcn_global_load_lds(
        (const __attribute__((address_space(1))) void*)(bptr + (size_t)(r * 32) * K + k0),
        (__attribute__((address_space(3))) void*)((char*)&Bs[0][0] + r * 4096 + lds_off),
        16, 0, 0);
    }
    __syncthreads();
    int lr = lane & 15, lk8 = (lane >> 4) * 8;
    #pragma unroll
    for (int kk = 0; kk < 2; ++kk) {
      bf16x8 af[4], bfv[4];
      #pragma unroll
      for (int m = 0; m < 4; ++m)
        af[m] = *reinterpret_cast<const bf16x8*>(&As[wm + m * 16 + lr][kk * 32 + lk8]);
      #pragma unroll
      for (int n = 0; n < 4; ++n)
        bfv[n] = *reinterpret_cast<const bf16x8*>(&Bs[wn + n * 16 + lr][kk * 32 + lk8]);
      #pragma unroll
      for (int m = 0; m < 4; ++m)
        #pragma unroll
        for (int n = 0; n < 4; ++n)
          acc[m][n] = __builtin_amdgcn_mfma_f32_16x16x32_bf16(af[m], bfv[n], acc[m][n], 0, 0, 0);
    }
    __syncthreads();
  }

  int crow0 = by * 128 + wm + (lane >> 4) * 4;
  int ccol0 = bx * 128 + wn + (lane & 15);
  #pragma unroll
  for (int m = 0; m < 4; ++m)
    #pragma unroll
    for (int n = 0; n < 4; ++n)
      #pragma unroll
      for (int j = 0; j < 4; ++j)
        S[(size_t)(crow0 + m * 16 + j) * NCOLS + ccol0 + n * 16] = f2bf(acc[m][n][j]);
}

// ---------------- Kernel C1: gates + value-norm scalars ---------------------
// per (t,g): gate = sigmoid(qn.kn/sqrt(512)); a = gate*rsqrt(gate^2*msv+eps)
__global__ __launch_bounds__(256) void gate_kernel(
    const float* __restrict__ hidden,   // (T,4,512)
    const u16* __restrict__ S,          // (T,2560) bf16
    const float* __restrict__ qw, const float* __restrict__ kw,
    float* __restrict__ gateA,          // (T,4)
    float* __restrict__ aA) {           // (T,4)
  __shared__ float red[4];
  int t = blockIdx.x;
  int g = threadIdx.x >> 6;
  int lane = threadIdx.x & 63;
  int base = lane * 8;

  // msv: mean(vraw^2) over 512, block-wide (2 elems/thread)
  const u16* vp = S + (size_t)t * 2560 + 2048;
  u16x2 vv = *(const u16x2*)(vp + threadIdx.x * 2);
  float v0 = bf2f(vv[0]), v1 = bf2f(vv[1]);
  float vs = wave_sum(v0 * v0 + v1 * v1);
  if (lane == 0) red[g] = vs;

  const float* hp = hidden + (size_t)t * 2048 + g * 512 + base;
  const u16*  kp = S + (size_t)t * 2560 + g * 512 + base;
  float4 q0 = *(const float4*)hp;
  float4 q1 = *(const float4*)(hp + 4);
  float q[8] = {q0.x, q0.y, q0.z, q0.w, q1.x, q1.y, q1.z, q1.w};
  u16x8 k8 = *(const u16x8*)kp;
  float4 qw0 = *(const float4*)(qw + g * 512 + base);
  float4 qw1 = *(const float4*)(qw + g * 512 + base + 4);
  float4 kw0 = *(const float4*)(kw + g * 512 + base);
  float4 kw1 = *(const float4*)(kw + g * 512 + base + 4);
  float qwv[8] = {qw0.x, qw0.y, qw0.z, qw0.w, qw1.x, qw1.y, qw1.z, qw1.w};
  float kwv[8] = {kw0.x, kw0.y, kw0.z, kw0.w, kw1.x, kw1.y, kw1.z, kw1.w};

  float qss = 0.f, kss = 0.f, qk = 0.f;
  #pragma unroll
  for (int j = 0; j < 8; ++j) {
    float k = bf2f(k8[j]);
    qss += q[j] * q[j];
    kss += k * k;
    qk  += q[j] * qwv[j] * k * kwv[j];
  }
  wave_sum3(qss, kss, qk);
  __syncthreads();
  float msv = (red[0] + red[1] + red[2] + red[3]) * (1.0f / 512.0f);

  float qinv = rsqrtf(qss * (1.0f / 512.0f) + EPS_N);
  float kinv = rsqrtf(kss * (1.0f / 512.0f) + EPS_N);
  float dot = qk * qinv * kinv;
  float gate = 1.0f / (1.0f + __expf(-dot * 0.04419417382415922f));
  float vinv = rsqrtf(gate * gate * msv + EPS_N);
  if (lane == 0) {
    gateA[t * 4 + g] = gate;
    aA[t * 4 + g] = gate * vinv;
  }
}

// ---------------- Kernel C2: value + dilated conv + silu + write out --------
// out[t,cf] = gate[t,g]*vraw[t,h] + silu( sum_k wc[k][cf]*a[tk,g]*vraw[tk,h] )
__global__ __launch_bounds__(256) void out_kernel(
    const u16* __restrict__ S,          // vraw at S[t*2560+2048+h]
    const float* __restrict__ gateA, const float* __restrict__ aA,
    const float* __restrict__ wc,       // [4][2048]
    float* __restrict__ out) {
  int idx = blockIdx.x * 256 + threadIdx.x;  // T*256 threads, 8 ch each
  int t = idx >> 8;                          // uniform per block
  int c8 = (idx & 255) * 8;
  int g = c8 >> 9;                           // uniform per wave
  int h = c8 & 511;

  float acc[8] = {0.f, 0.f, 0.f, 0.f, 0.f, 0.f, 0.f, 0.f};
  float vr_t[8];
  #pragma unroll
  for (int k = 0; k < 4; ++k) {
    int tk = t - 12 + 4 * k;
    if (tk < 0) { if (k == 3) { /* unreachable: tk=t>=0 */ } continue; }
    float s = aA[tk * 4 + g];
    u16x8 vv = *(const u16x8*)&S[(size_t)tk * 2560 + 2048 + h];
    float4 w0 = *(const float4*)(wc + k * 2048 + c8);
    float4 w1 = *(const float4*)(wc + k * 2048 + c8 + 4);
    float w8[8] = {w0.x, w0.y, w0.z, w0.w, w1.x, w1.y, w1.z, w1.w};
    #pragma unroll
    for (int j = 0; j < 8; ++j) {
      float v = bf2f(vv[j]);
      acc[j] += w8[j] * s * v;
      if (k == 3) vr_t[j] = v;
    }
  }
  float gate = gateA[t * 4 + g];
  float r[8];
  #pragma unroll
  for (int j = 0; j < 8; ++j) {
    float y = acc[j];
    r[j] = gate * vr_t[j] + y / (1.0f + __expf(-y));
  }
  float* op = out + (size_t)t * 2048 + c8;
  *(float4*)op       = make_float4(r[0], r[1], r[2], r[3]);
  *(float4*)(op + 4) = make_float4(r[4], r[5], r[6], r[7]);
}

extern "C" void kernel_launch(void* const* d_in, const int* in_sizes, int n_in,
                              void* d_out, int out_size, void* d_ws, size_t ws_size,
                              hipStream_t stream) {
  const int*   hash_ids = (const int*)d_in[0];
  const int*   offsets  = (const int*)d_in[1];
  const float* emb_w    = (const float*)d_in[2];
  const float* kp       = (const float*)d_in[3];
  const float* qw       = (const float*)d_in[4];
  const float* kw       = (const float*)d_in[5];
  const float* vp       = (const float*)d_in[6];
  const float* conv_w   = (const float*)d_in[7];
  const float* cw       = (const float*)d_in[8];
  const float* hidden   = (const float*)d_in[9];
  float* out = (float*)d_out;
  char*  ws  = (char*)d_ws;

  u16*   S     = (u16*)ws;                       // 83,886,080 B
  u16*   emb   = (u16*)(ws + 83886080);          // 25,165,824 B
  u16*   wt    = (u16*)(ws + 109051904);         //  3,932,160 B
  float* gateA = (float*)(ws + 112984064);       //    262,144 B
  float* aA    = (float*)(ws + 113246208);       //    262,144 B
  float* wc    = (float*)(ws + 113508352);       //     32,768 B

  gather_emb<<<(T_TOK * E_DIM) / 256, 256, 0, stream>>>(hash_ids, offsets, emb_w, emb);
  build_wcat<<<dim3(16, 24, 5), dim3(32, 8), 0, stream>>>(kp, vp, wt);
  build_wc<<<8, 256, 0, stream>>>(conv_w, cw, wc);
  gemm_bf16<<<dim3(20, 128), 256, 0, stream>>>(emb, wt, S);
  gate_kernel<<<T_TOK, 256, 0, stream>>>(hidden, S, qw, kw, gateA, aA);
  out_kernel<<<T_TOK * 256 / 256, 256, 0, stream>>>(S, gateA, aA, wc, out);
}

// Round 3
// 196.566 us; speedup vs baseline: 1.4400x; 1.0443x over previous
//
#include <hip/hip_runtime.h>
#include <hip/hip_bf16.h>
#include <math.h>

#define T_TOK  16384
#define H_DIM  512
#define NHEADS 12
#define E_DIM  768
#define EPS_N  1e-5f
#define QK_SCALE 0.04419417382415922f

typedef unsigned short u16;
typedef __bf16 bf16;
typedef bf16   bf16x8 __attribute__((ext_vector_type(8)));
typedef float  f32x4  __attribute__((ext_vector_type(4)));
typedef u16    u16x8  __attribute__((ext_vector_type(8)));

__device__ __forceinline__ u16 f2bf(float f) {
  unsigned u = __builtin_bit_cast(unsigned, f);
  unsigned r = u + 0x7fffu + ((u >> 16) & 1u);
  return (u16)(r >> 16);
}
__device__ __forceinline__ float bf2f(u16 h) {
  unsigned u = ((unsigned)h) << 16;
  return __builtin_bit_cast(float, u);
}

// ---------------- Kernel A: gather embedding rows, cast to bf16 -------------
// 8 threads per (t,head) row: each reads 32 B fp32, writes 16 B bf16.
__global__ __launch_bounds__(256) void gather_emb(
    const int* __restrict__ hash_ids, const int* __restrict__ offsets,
    const float* __restrict__ emb_w, u16* __restrict__ emb) {
  int idx = blockIdx.x * 256 + threadIdx.x;        // T*12*8
  int pair = idx >> 3;                             // t*12 + head
  int sub = idx & 7;
  int t = pair / 12;
  int head = pair - t * 12;
  int row = hash_ids[pair] + offsets[head];
  const float* src = emb_w + (size_t)row * 64 + sub * 8;
  float4 a = *(const float4*)src;
  float4 b = *(const float4*)(src + 4);
  u16x8 o;
  o[0] = f2bf(a.x); o[1] = f2bf(a.y); o[2] = f2bf(a.z); o[3] = f2bf(a.w);
  o[4] = f2bf(b.x); o[5] = f2bf(b.y); o[6] = f2bf(b.z); o[7] = f2bf(b.w);
  *(u16x8*)(emb + (size_t)t * E_DIM + head * 64 + sub * 8) = o;
}

// ---------------- Kernel A2: build WcatT (2560 x 768) bf16 ------------------
__global__ __launch_bounds__(256) void build_wcat(
    const float* __restrict__ kp, const float* __restrict__ vp,
    u16* __restrict__ wt) {
  __shared__ float tile[32][33];
  int m = blockIdx.z;
  const float* src = (m < 4) ? (kp + (size_t)m * E_DIM * H_DIM) : vp;
  int h0 = blockIdx.x * 32, e0 = blockIdx.y * 32;
  int tx = threadIdx.x, ty = threadIdx.y;          // block (32,8)
  #pragma unroll
  for (int j = 0; j < 32; j += 8)
    tile[ty + j][tx] = src[(size_t)(e0 + ty + j) * H_DIM + h0 + tx];
  __syncthreads();
  #pragma unroll
  for (int j = 0; j < 32; j += 8) {
    int h = h0 + ty + j, e = e0 + tx;
    wt[(size_t)(m * H_DIM + h) * E_DIM + e] = f2bf(tile[tx][ty + j]);
  }
}

// ---------------- Kernel A3: fold conv_norm_w into conv weights -------------
__global__ __launch_bounds__(256) void build_wc(
    const float* __restrict__ conv_w, const float* __restrict__ cnw,
    float* __restrict__ wc) {
  int cf = blockIdx.x * 256 + threadIdx.x;         // 2048
  float c = cnw[cf];
  #pragma unroll
  for (int k = 0; k < 4; ++k) wc[k * 2048 + cf] = conv_w[cf * 4 + k] * c;
}

// ---------------- Kernel B: GEMM + fused gate-reduction epilogue ------------
// C = A(16384x768) * BT^T. bx<16: key cols -> reduce k^2, q*qw*k*kw, q^2 per
// row, store per-(t,g,quarter) partials (nothing else written).
// bx>=16: vraw cols -> store V bf16 + per-row sum v^2 partial.
__global__ __launch_bounds__(256, 2) void gemm_bf16(
    const u16* __restrict__ A, const u16* __restrict__ BT,
    const float* __restrict__ hidden, const float* __restrict__ qw,
    const float* __restrict__ kw,
    u16* __restrict__ V, float* __restrict__ kssP, float* __restrict__ qkP,
    float* __restrict__ qssP, float* __restrict__ msvP) {
  __shared__ u16 As[128][64];
  __shared__ u16 Bs[128][64];
  __shared__ float part[2][128][3];
  const int K = E_DIM;
  int tid = threadIdx.x;
  int lane = tid & 63, wid = tid >> 6;
  int bx = blockIdx.x, by = blockIdx.y;
  int wm = (wid >> 1) * 64, wn = (wid & 1) * 64;
  int widN = wid & 1;

  const u16* aptr = A + (size_t)(by * 128 + (tid >> 3)) * K + (tid & 7) * 8;
  const u16* bptr = BT + (size_t)(bx * 128 + (tid >> 3)) * K + (tid & 7) * 8;
  int lds_off = tid * 16;

  f32x4 acc[4][4] = {};

  for (int k0 = 0; k0 < K; k0 += 64) {
    #pragma unroll
    for (int r = 0; r < 4; ++r) {
      __builtin_amdgcn_global_load_lds(
        (const __attribute__((address_space(1))) void*)(aptr + (size_t)(r * 32) * K + k0),
        (__attribute__((address_space(3))) void*)((char*)&As[0][0] + r * 4096 + lds_off),
        16, 0, 0);
      __builtin_amdgcn_global_load_lds(
        (const __attribute__((address_space(1))) void*)(bptr + (size_t)(r * 32) * K + k0),
        (__attribute__((address_space(3))) void*)((char*)&Bs[0][0] + r * 4096 + lds_off),
        16, 0, 0);
    }
    __syncthreads();
    int lr = lane & 15, lk8 = (lane >> 4) * 8;
    #pragma unroll
    for (int kk = 0; kk < 2; ++kk) {
      bf16x8 af[4], bfv[4];
      #pragma unroll
      for (int m = 0; m < 4; ++m)
        af[m] = *reinterpret_cast<const bf16x8*>(&As[wm + m * 16 + lr][kk * 32 + lk8]);
      #pragma unroll
      for (int n = 0; n < 4; ++n)
        bfv[n] = *reinterpret_cast<const bf16x8*>(&Bs[wn + n * 16 + lr][kk * 32 + lk8]);
      #pragma unroll
      for (int m = 0; m < 4; ++m)
        #pragma unroll
        for (int n = 0; n < 4; ++n)
          acc[m][n] = __builtin_amdgcn_mfma_f32_16x16x32_bf16(af[m], bfv[n], acc[m][n], 0, 0, 0);
    }
    __syncthreads();
  }

  int lr16 = lane & 15, rgrp = lane >> 4;

  if (bx < 16) {
    // ---- key tile: fused reductions, no store of keys ----
    int g = bx >> 2, q = bx & 3;
    int colbase = g * 512 + q * 128 + wn + lr16;   // absolute hidden col
    float qwv[4], kwv[4];
    #pragma unroll
    for (int n = 0; n < 4; ++n) {
      qwv[n] = qw[colbase + n * 16];
      kwv[n] = kw[colbase + n * 16];
    }
    #pragma unroll
    for (int m = 0; m < 4; ++m) {
      #pragma unroll
      for (int j = 0; j < 4; ++j) {
        int r = wm + m * 16 + rgrp * 4 + j;        // block-local row
        size_t t = (size_t)(by * 128 + r);
        float sk2 = 0.f, sqk = 0.f, sq2 = 0.f;
        #pragma unroll
        for (int n = 0; n < 4; ++n) {
          float kv = acc[m][n][j];
          float qv = hidden[t * 2048 + colbase + n * 16];
          sk2 += kv * kv;
          sqk += (qv * qwv[n]) * (kv * kwv[n]);
          sq2 += qv * qv;
        }
        #pragma unroll
        for (int off = 1; off < 16; off <<= 1) {
          sk2 += __shfl_xor(sk2, off, 64);
          sqk += __shfl_xor(sqk, off, 64);
          sq2 += __shfl_xor(sq2, off, 64);
        }
        if (lr16 == 0) {
          part[widN][r][0] = sk2;
          part[widN][r][1] = sqk;
          part[widN][r][2] = sq2;
        }
      }
    }
    __syncthreads();
    if (tid < 128) {
      int t = by * 128 + tid;
      int o = (t * 4 + g) * 4 + q;
      kssP[o] = part[0][tid][0] + part[1][tid][0];
      qkP[o]  = part[0][tid][1] + part[1][tid][1];
      qssP[o] = part[0][tid][2] + part[1][tid][2];
    }
  } else {
    // ---- vraw tile: store bf16 V + per-row v^2 partial ----
    int q2 = bx - 16;
    #pragma unroll
    for (int m = 0; m < 4; ++m) {
      #pragma unroll
      for (int j = 0; j < 4; ++j) {
        int r = wm + m * 16 + rgrp * 4 + j;
        size_t t = (size_t)(by * 128 + r);
        float sv2 = 0.f;
        #pragma unroll
        for (int n = 0; n < 4; ++n) {
          float v = acc[m][n][j];
          sv2 += v * v;
          V[t * 512 + q2 * 128 + wn + n * 16 + lr16] = f2bf(v);
        }
        #pragma unroll
        for (int off = 1; off < 16; off <<= 1) sv2 += __shfl_xor(sv2, off, 64);
        if (lr16 == 0) part[widN][r][0] = sv2;
      }
    }
    __syncthreads();
    if (tid < 128) {
      int t = by * 128 + tid;
      msvP[t * 4 + q2] = part[0][tid][0] + part[1][tid][0];
    }
  }
}

// ---------------- Kernel C1: finish gates from partials ---------------------
__global__ __launch_bounds__(256) void gate_finish(
    const float* __restrict__ kssP, const float* __restrict__ qkP,
    const float* __restrict__ qssP, const float* __restrict__ msvP,
    float* __restrict__ gateA, float* __restrict__ aA) {
  int i = blockIdx.x * 256 + threadIdx.x;          // T*4
  int t = i >> 2;
  float4 k4 = *(const float4*)&kssP[i * 4];
  float4 d4 = *(const float4*)&qkP[i * 4];
  float4 q4 = *(const float4*)&qssP[i * 4];
  float4 m4 = *(const float4*)&msvP[t * 4];
  float kss = k4.x + k4.y + k4.z + k4.w;
  float qk  = d4.x + d4.y + d4.z + d4.w;
  float qss = q4.x + q4.y + q4.z + q4.w;
  float msv = (m4.x + m4.y + m4.z + m4.w) * (1.0f / 512.0f);
  float qinv = rsqrtf(qss * (1.0f / 512.0f) + EPS_N);
  float kinv = rsqrtf(kss * (1.0f / 512.0f) + EPS_N);
  float gate = 1.0f / (1.0f + __expf(-qk * qinv * kinv * QK_SCALE));
  gateA[i] = gate;
  aA[i] = gate * rsqrtf(gate * gate * msv + EPS_N);
}

// ---------------- Kernel C2: value + dilated conv + silu + write out --------
__global__ __launch_bounds__(256) void out_kernel(
    const u16* __restrict__ V,          // (T,512) bf16
    const float* __restrict__ gateA, const float* __restrict__ aA,
    const float* __restrict__ wc,       // [4][2048]
    float* __restrict__ out) {
  int idx = blockIdx.x * 256 + threadIdx.x;  // T*256 threads, 8 ch each
  int t = idx >> 8;
  int c8 = (idx & 255) * 8;
  int g = c8 >> 9;
  int h = c8 & 511;

  float acc[8] = {0.f, 0.f, 0.f, 0.f, 0.f, 0.f, 0.f, 0.f};
  float vr_t[8];
  #pragma unroll
  for (int k = 0; k < 4; ++k) {
    int tk = t - 12 + 4 * k;
    if (tk < 0) continue;
    float s = aA[tk * 4 + g];
    u16x8 vv = *(const u16x8*)&V[(size_t)tk * 512 + h];
    float4 w0 = *(const float4*)(wc + k * 2048 + c8);
    float4 w1 = *(const float4*)(wc + k * 2048 + c8 + 4);
    float w8[8] = {w0.x, w0.y, w0.z, w0.w, w1.x, w1.y, w1.z, w1.w};
    #pragma unroll
    for (int j = 0; j < 8; ++j) {
      float v = bf2f(vv[j]);
      acc[j] += w8[j] * s * v;
      if (k == 3) vr_t[j] = v;
    }
  }
  float gate = gateA[t * 4 + g];
  float r[8];
  #pragma unroll
  for (int j = 0; j < 8; ++j) {
    float y = acc[j];
    r[j] = gate * vr_t[j] + y / (1.0f + __expf(-y));
  }
  float* op = out + (size_t)t * 2048 + c8;
  *(float4*)op       = make_float4(r[0], r[1], r[2], r[3]);
  *(float4*)(op + 4) = make_float4(r[4], r[5], r[6], r[7]);
}

extern "C" void kernel_launch(void* const* d_in, const int* in_sizes, int n_in,
                              void* d_out, int out_size, void* d_ws, size_t ws_size,
                              hipStream_t stream) {
  const int*   hash_ids = (const int*)d_in[0];
  const int*   offsets  = (const int*)d_in[1];
  const float* emb_w    = (const float*)d_in[2];
  const float* kp       = (const float*)d_in[3];
  const float* qw       = (const float*)d_in[4];
  const float* kw       = (const float*)d_in[5];
  const float* vp       = (const float*)d_in[6];
  const float* conv_w   = (const float*)d_in[7];
  const float* cw       = (const float*)d_in[8];
  const float* hidden   = (const float*)d_in[9];
  float* out = (float*)d_out;
  char*  ws  = (char*)d_ws;

  u16*   V     = (u16*)ws;                       // 16,777,216
  u16*   emb   = (u16*)(ws + 16777216);          // 25,165,824
  u16*   wt    = (u16*)(ws + 41943040);          //  3,932,160
  float* kssP  = (float*)(ws + 45875200);        //  1,048,576
  float* qkP   = (float*)(ws + 46923776);        //  1,048,576
  float* qssP  = (float*)(ws + 47972352);        //  1,048,576
  float* msvP  = (float*)(ws + 49020928);        //    262,144
  float* gateA = (float*)(ws + 49283072);        //    262,144
  float* aA    = (float*)(ws + 49545216);        //    262,144
  float* wc    = (float*)(ws + 49807360);        //     32,768

  gather_emb<<<(T_TOK * 12 * 8) / 256, 256, 0, stream>>>(hash_ids, offsets, emb_w, emb);
  build_wcat<<<dim3(16, 24, 5), dim3(32, 8), 0, stream>>>(kp, vp, wt);
  build_wc<<<8, 256, 0, stream>>>(conv_w, cw, wc);
  gemm_bf16<<<dim3(20, 128), 256, 0, stream>>>(emb, wt, hidden, qw, kw,
                                               V, kssP, qkP, qssP, msvP);
  gate_finish<<<(T_TOK * 4) / 256, 256, 0, stream>>>(kssP, qkP, qssP, msvP, gateA, aA);
  out_kernel<<<T_TOK * 256 / 256, 256, 0, stream>>>(V, gateA, aA, wc, out);
}